// Round 2
// baseline (502.664 us; speedup 1.0000x reference)
//
#include <hip/hip_runtime.h>

#define NB 32
#define N1 512
#define N2 512
#define DF 128
#define MW 256
#define KD 96
#define INVG 10.0f
#define GAM 0.1f
#define BARRIER 10000.0f

// ws layout (floats)
#define WS_T1MAX 0
#define WS_T2MAX (NB)
#define WS_NODE  (2*NB)
#define WS_ABUF  (WS_NODE + NB*MW*KD)
#define WS_BBUF  (WS_ABUF + NB*MW*KD)

__device__ __forceinline__ bool feq(float a, float b) {
  return fabsf(a - b) <= 1e-4f * fmaxf(fabsf(a), fabsf(b)) + 1e-12f;
}

// ---------------- K0: per-b max of t1, t2 ----------------
__global__ __launch_bounds__(256) void k0_rowmax(const float* __restrict__ t1,
                                                 const float* __restrict__ t2,
                                                 float* __restrict__ ws) {
  int b = blockIdx.x;
  int t = threadIdx.x;
  float m1 = -1e30f, m2 = -1e30f;
  for (int i = t; i < N1; i += 256) m1 = fmaxf(m1, t1[b*N1+i]);
  for (int i = t; i < N2; i += 256) m2 = fmaxf(m2, t2[b*N2+i]);
  __shared__ float sm1[4], sm2[4];
  #pragma unroll
  for (int o = 32; o; o >>= 1) {
    m1 = fmaxf(m1, __shfl_down(m1, o));
    m2 = fmaxf(m2, __shfl_down(m2, o));
  }
  int wv = t >> 6;
  if ((t & 63) == 0) { sm1[wv] = m1; sm2[wv] = m2; }
  __syncthreads();
  if (t == 0) {
    ws[WS_T1MAX + b] = fmaxf(fmaxf(sm1[0], sm1[1]), fmaxf(sm1[2], sm1[3]));
    ws[WS_T2MAX + b] = fmaxf(fmaxf(sm2[0], sm2[1]), fmaxf(sm2[2], sm2[3]));
  }
}

// ---------------- K1: node costs ----------------
__global__ __launch_bounds__(256) void k1_node(const float* __restrict__ s1f,
                                               const float* __restrict__ s2f,
                                               const float* __restrict__ tw,
                                               const float* __restrict__ glb_lb,
                                               const float* __restrict__ glb_ub,
                                               float* __restrict__ ws) {
  const int m = blockIdx.x;
  const int b = blockIdx.y;
  const int t = threadIdx.x;
  const int lane = t & 63;
  const int wv = t >> 6;
  __shared__ float s1s[DF];
  const float T1 = ws[WS_T1MAX + b];
  const float T2 = ws[WS_T2MAX + b];
  const float twm = tw[b*MW + m];
  float wts;
  {
    float prev = (m > 0) ? tw[b*MW + m - 1] : twm;
    float next = (m < MW-1) ? tw[b*MW + m + 1] : twm;
    wts = 0.5f * (next - prev);
  }
  const float lb = glb_lb[b*MW+m] * T2;
  const float ub = glb_ub[b*MW+m] * T2;

  if (t < DF) {
    float pos = twm / T1;
    float x = fminf(fmaxf(pos, 0.f), 1.f) * (float)(N1-1);
    int i0 = (int)x; i0 = max(0, min(i0, N1-2));
    float w = x - (float)i0;
    const float* r0 = s1f + ((size_t)b*N1 + i0)*DF;
    s1s[t] = r0[t] + (r0[DF + t] - r0[t]) * w;
  }
  __syncthreads();

  const float invT2 = 1.0f / T2;
  for (int kk = 0; kk < KD/4; kk++) {
    const int k = wv * (KD/4) + kk;
    const float fr = (float)k * (1.0f/95.0f);
    const float tauk = lb + (ub - lb) * fr;
    float pos = tauk * invT2;
    float x = fminf(fmaxf(pos, 0.f), 1.f) * (float)(N2-1);
    int i0 = (int)x; i0 = max(0, min(i0, N2-2));
    float w = x - (float)i0;
    const float2* r0 = (const float2*)(s2f + ((size_t)b*N2 + i0)*DF);
    const float2* r1 = (const float2*)(s2f + ((size_t)b*N2 + i0 + 1)*DF);
    float2 f0 = r0[lane];
    float2 f1 = r1[lane];
    float a0 = f0.x + (f1.x - f0.x)*w;
    float a1 = f0.y + (f1.y - f0.y)*w;
    float d0 = s1s[2*lane]   - a0;
    float d1 = s1s[2*lane+1] - a1;
    float part = d0*d0 + d1*d1;
    #pragma unroll
    for (int o = 32; o; o >>= 1) part += __shfl_down(part, o);
    if (lane == 0) {
      float node = part * wts;
      if (m == 0)    node += BARRIER * tauk * tauk;
      if (m == MW-1) { float dd = tauk - T2; node += BARRIER * dd * dd; }
      ws[WS_NODE + ((size_t)b*MW + m)*KD + k] = node;
    }
  }
}

// ---------------- K2: forward/backward DP, LOG domain ----------------
// 384 threads: thread t -> (kk = t>>2, h = t&3). Each quad computes one
// softmin over 96 j's (24 per thread), combined via quad shuffles.
__global__ __launch_bounds__(384) void k2_dp(const float* __restrict__ tw,
                                             const float* __restrict__ glb_lb,
                                             const float* __restrict__ glb_ub,
                                             const float* __restrict__ reg_wt,
                                             const float* __restrict__ gubp,
                                             float* __restrict__ ws) {
  const int dir = blockIdx.x;   // 0 fwd, 1 bwd
  const int b = blockIdx.y;
  const int t = threadIdx.x;    // 0..383
  const int kk = t >> 2;        // 0..95
  const int h  = t & 3;
  __shared__ float lbw[MW], ubw[MW], twv[MW];
  __shared__ float sA[KD];
  const float T2 = ws[WS_T2MAX + b];
  for (int i = t; i < MW; i += 384) {
    lbw[i] = glb_lb[b*MW+i] * T2;
    ubw[i] = glb_ub[b*MW+i] * T2;
    twv[i] = tw[b*MW+i];
  }
  const float r = reg_wt[b];
  const float gub = gubp[b];
  const float frk = (float)kk * (1.0f/95.0f);
  const float* __restrict__ node = ws + WS_NODE + (size_t)b*MW*KD;
  float* __restrict__ outbuf = ws + ((dir==0)?WS_ABUF:WS_BBUF) + (size_t)b*MW*KD;

  float ereg[24];
  #pragma unroll
  for (int j = 0; j < 24; j++) ereg[j] = 0.f;
  float cL1 = __int_as_float(0x7fc00000);
  float cU1 = cL1, cL2 = cL1, cU2 = cL1, cdt = cL1;

  __syncthreads();
  if (h == 0) {
    if (dir == 0) {
      float v = node[kk];                 // alpha_0 = node[0]
      sA[kk] = v;
      outbuf[kk] = v;
    } else {
      sA[kk] = node[(size_t)(MW-1)*KD + kk];   // C_{M-1} = node + beta(=0)
      outbuf[(size_t)(MW-1)*KD + kk] = 0.0f;
    }
  }
  __syncthreads();

  for (int step = 0; step < MW-1; step++) {
    const int i = (dir==0) ? step : (MW-2-step);
    const int m1 = i, m2 = i+1;
    const float L1 = lbw[m1], U1 = ubw[m1], L2 = lbw[m2], U2 = ubw[m2];
    const float dt = twv[m2] - twv[m1];
    if (!(feq(L1,cL1) && feq(U1,cU1) && feq(L2,cL2) && feq(U2,cU2) && feq(dt,cdt))) {
      cL1=L1; cU1=U1; cL2=L2; cU2=U2; cdt=dt;
      const float invdt = 1.0f/dt, rdt = r*dt;
      const float mytau = (dir==0) ? (L2+(U2-L2)*frk) : (L1+(U1-L1)*frk);
      #pragma unroll
      for (int jj = 0; jj < 24; jj++) {
        const float frj = (float)(4*jj + h) * (1.0f/95.0f);
        const float oth = (dir==0) ? (L1+(U1-L1)*frj) : (L2+(U2-L2)*frj);
        const float slope = ((dir==0) ? (mytau-oth) : (oth-mytau)) * invdt;
        const float sm1 = slope - 1.0f;
        const float ng = fminf(slope, 0.f);
        const float ov = fmaxf(slope - gub, 0.f);
        ereg[jj] = rdt*sm1*sm1 + BARRIER*(ng*ng + ov*ov);
      }
    }
    // pass 1: min over all 96 j's (24 here + quad combine)
    float mn = 1e30f;
    #pragma unroll
    for (int jj = 0; jj < 24; jj++) {
      float x = sA[4*jj + h] + ereg[jj];
      mn = fminf(mn, x);
    }
    mn = fminf(mn, __shfl_xor(mn, 1));
    mn = fminf(mn, __shfl_xor(mn, 2));
    // pass 2: sum of exp((mn - x)/gamma)
    float sum = 0.f;
    #pragma unroll
    for (int jj = 0; jj < 24; jj++) {
      float x = sA[4*jj + h] + ereg[jj];
      sum += __expf((mn - x) * INVG);
    }
    sum += __shfl_xor(sum, 1);
    sum += __shfl_xor(sum, 2);
    const float sval = mn - GAM * __logf(sum);   // softmin
    __syncthreads();
    if (h == 0) {
      if (dir == 0) {
        float v = node[(size_t)m2*KD + kk] + sval;  // alpha_{m2}
        sA[kk] = v;
        outbuf[(size_t)m2*KD + kk] = v;
      } else {
        float ndm1 = node[(size_t)m1*KD + kk];
        outbuf[(size_t)m1*KD + kk] = sval;          // beta_{m1}
        sA[kk] = sval + ndm1;                       // C_{m1}
      }
    }
    __syncthreads();
  }
}

// ---------------- K3: softmax readout (log domain in) ----------------
__global__ __launch_bounds__(256) void k3_final(const float* __restrict__ glb_lb,
                                                const float* __restrict__ glb_ub,
                                                const float* __restrict__ ws,
                                                float* __restrict__ out) {
  const int wv = threadIdx.x >> 6;
  const int lane = threadIdx.x & 63;
  const int gw = blockIdx.x * 4 + wv;      // 0..8191 = b*256+m
  const int b = gw >> 8, m = gw & 255;
  const float T2 = ws[WS_T2MAX + b];
  const float lb = glb_lb[b*MW+m] * T2;
  const float ub = glb_ub[b*MW+m] * T2;
  const float* __restrict__ Ab = ws + WS_ABUF + (size_t)gw*KD;
  const float* __restrict__ Bb = ws + WS_BBUF + (size_t)gw*KD;
  float s0 = Ab[lane] + Bb[lane];
  float s1 = 1e30f;
  if (lane < KD - 64) s1 = Ab[lane+64] + Bb[lane+64];
  float mn = fminf(s0, s1);
  #pragma unroll
  for (int o = 32; o; o >>= 1) mn = fminf(mn, __shfl_xor(mn, o));
  const float tau0 = lb + (ub-lb) * (float)lane * (1.0f/95.0f);
  const float tau1 = lb + (ub-lb) * (float)(lane+64) * (1.0f/95.0f);
  float w0 = __expf((mn - s0) * INVG);
  float w1 = __expf((mn - s1) * INVG);     // 0 for inactive lanes
  float num = w0*tau0 + w1*tau1;
  float den = w0 + w1;
  #pragma unroll
  for (int o = 32; o; o >>= 1) {
    num += __shfl_down(num, o);
    den += __shfl_down(den, o);
  }
  if (lane == 0) out[gw] = num / den;
}

extern "C" void kernel_launch(void* const* d_in, const int* in_sizes, int n_in,
                              void* d_out, int out_size, void* d_ws, size_t ws_size,
                              hipStream_t stream) {
  const float* s1f    = (const float*)d_in[0];
  const float* s2f    = (const float*)d_in[1];
  const float* regw   = (const float*)d_in[2];
  const float* glb_lb = (const float*)d_in[3];
  const float* glb_ub = (const float*)d_in[4];
  const float* gubp   = (const float*)d_in[5];
  const float* t1     = (const float*)d_in[6];
  const float* t2     = (const float*)d_in[7];
  const float* twp    = (const float*)d_in[8];
  float* ws  = (float*)d_ws;
  float* out = (float*)d_out;

  k0_rowmax<<<NB, 256, 0, stream>>>(t1, t2, ws);
  dim3 g1(MW, NB);
  k1_node<<<g1, 256, 0, stream>>>(s1f, s2f, twp, glb_lb, glb_ub, ws);
  dim3 g2(2, NB);
  k2_dp<<<g2, 384, 0, stream>>>(twp, glb_lb, glb_ub, regw, gubp, ws);
  k3_final<<<MW*NB/4, 256, 0, stream>>>(glb_lb, glb_ub, ws, out);
}

// Round 3
// 360.106 us; speedup vs baseline: 1.3959x; 1.3959x over previous
//
#include <hip/hip_runtime.h>

#define NB 32
#define N1 512
#define N2 512
#define DF 128
#define MW 256
#define KD 96
#define INVG 10.0f
#define GAM 0.1f
#define BARRIER 10000.0f
#define MARGIN 200.0f

// ws layout (floats)
#define WS_T1MAX 0
#define WS_T2MAX (NB)
#define WS_NDMIN (2*NB)
#define WS_NODE  (WS_NDMIN + NB*MW)
#define WS_ABUF  (WS_NODE + NB*MW*KD)
#define WS_BBUF  (WS_ABUF + NB*MW*KD)

__device__ __forceinline__ bool feq(float a, float b) {
  return fabsf(a - b) <= 1e-4f * fmaxf(fabsf(a), fabsf(b)) + 1e-12f;
}

// ---------------- K0: per-b max of t1, t2 ----------------
__global__ __launch_bounds__(256) void k0_rowmax(const float* __restrict__ t1,
                                                 const float* __restrict__ t2,
                                                 float* __restrict__ ws) {
  int b = blockIdx.x;
  int t = threadIdx.x;
  float m1 = -1e30f, m2 = -1e30f;
  for (int i = t; i < N1; i += 256) m1 = fmaxf(m1, t1[b*N1+i]);
  for (int i = t; i < N2; i += 256) m2 = fmaxf(m2, t2[b*N2+i]);
  __shared__ float sm1[4], sm2[4];
  #pragma unroll
  for (int o = 32; o; o >>= 1) {
    m1 = fmaxf(m1, __shfl_down(m1, o));
    m2 = fmaxf(m2, __shfl_down(m2, o));
  }
  int wv = t >> 6;
  if ((t & 63) == 0) { sm1[wv] = m1; sm2[wv] = m2; }
  __syncthreads();
  if (t == 0) {
    ws[WS_T1MAX + b] = fmaxf(fmaxf(sm1[0], sm1[1]), fmaxf(sm1[2], sm1[3]));
    ws[WS_T2MAX + b] = fmaxf(fmaxf(sm2[0], sm2[1]), fmaxf(sm2[2], sm2[3]));
  }
}

// ---------------- K1: node costs (tiled distance matrix) ----------------
// grid (8 m-tiles, NB b), 256 threads. s2 interp cached on the m0 (lb,ub) grid;
// per-m fallback to direct interp if that m's (lb,ub) differs.
__global__ __launch_bounds__(256) void k1_node(const float* __restrict__ s1f,
                                               const float* __restrict__ s2f,
                                               const float* __restrict__ tw,
                                               const float* __restrict__ glb_lb,
                                               const float* __restrict__ glb_ub,
                                               float* __restrict__ ws) {
  const int mb = blockIdx.x;
  const int b  = blockIdx.y;
  const int t  = threadIdx.x;
  __shared__ float s1L[32*132];
  __shared__ float s2L[96*132];
  __shared__ float ndt[32*99];
  __shared__ float wtsL[32], lbL[32], ubL[32];
  __shared__ int   matchL[32];
  const float T1 = ws[WS_T1MAX + b];
  const float T2 = ws[WS_T2MAX + b];
  const float lb0 = glb_lb[b*MW] * T2;
  const float ub0 = glb_ub[b*MW] * T2;
  float4* s1L4 = (float4*)s1L;
  float4* s2L4 = (float4*)s2L;
  const float4* s1f4 = (const float4*)(s1f + (size_t)b*N1*DF);
  const float4* s2f4 = (const float4*)(s2f + (size_t)b*N2*DF);

  // stage A: s2 interp on m0 tau-grid -> s2L
  {
    const int d32 = t & 31;
    const int k8  = t >> 5;
    for (int kk = 0; kk < 12; kk++) {
      int k = k8 + 8*kk;
      float tau = lb0 + (ub0 - lb0) * (float)k * (1.0f/95.0f);
      float x = fminf(fmaxf(tau / T2, 0.f), 1.f) * (float)(N2-1);
      int i0 = (int)x; i0 = max(0, min(i0, N2-2));
      float w = x - (float)i0;
      float4 f0 = s2f4[(size_t)i0*32 + d32];
      float4 f1 = s2f4[(size_t)(i0+1)*32 + d32];
      float4 r;
      r.x = f0.x + (f1.x - f0.x)*w; r.y = f0.y + (f1.y - f0.y)*w;
      r.z = f0.z + (f1.z - f0.z)*w; r.w = f0.w + (f1.w - f0.w)*w;
      s2L4[k*33 + d32] = r;
    }
  }
  // stage B: s1 interp -> s1L
  {
    const int mi = t >> 3, q = t & 7;
    const int m = mb*32 + mi;
    float twm = tw[b*MW + m];
    float x = fminf(fmaxf(twm / T1, 0.f), 1.f) * (float)(N1-1);
    int i0 = (int)x; i0 = max(0, min(i0, N1-2));
    float w = x - (float)i0;
    #pragma unroll
    for (int j = 0; j < 4; j++) {
      int d4 = q + 8*j;
      float4 f0 = s1f4[(size_t)i0*32 + d4];
      float4 f1 = s1f4[(size_t)(i0+1)*32 + d4];
      float4 r;
      r.x = f0.x + (f1.x - f0.x)*w; r.y = f0.y + (f1.y - f0.y)*w;
      r.z = f0.z + (f1.z - f0.z)*w; r.w = f0.w + (f1.w - f0.w)*w;
      s1L4[mi*33 + d4] = r;
    }
  }
  if (t < 32) {
    int m = mb*32 + t, g = b*MW + m;
    float twm = tw[g];
    float prev = (m > 0) ? tw[g-1] : twm;
    float next = (m < MW-1) ? tw[g+1] : twm;
    wtsL[t] = 0.5f*(next - prev);
    float lbm = glb_lb[g]*T2, ubm = glb_ub[g]*T2;
    lbL[t] = lbm; ubL[t] = ubm;
    matchL[t] = (feq(lbm, lb0) && feq(ubm, ub0)) ? 1 : 0;
  }
  __syncthreads();

  const int mi = t >> 3, kg = t & 7;
  const int m = mb*32 + mi;
  float acc[12];
  #pragma unroll
  for (int i = 0; i < 12; i++) acc[i] = 0.f;
  if (matchL[mi]) {
    for (int d4 = 0; d4 < 32; d4++) {
      float4 s1v = s1L4[mi*33 + d4];
      #pragma unroll
      for (int k12 = 0; k12 < 12; k12++) {
        int k = kg + 8*k12;
        float4 s2v = s2L4[k*33 + d4];
        float dx = s1v.x - s2v.x, dy = s1v.y - s2v.y;
        float dz = s1v.z - s2v.z, dw = s1v.w - s2v.w;
        acc[k12] += dx*dx + dy*dy + dz*dz + dw*dw;
      }
    }
  } else {
    // slow generic path: direct interp from s2f on this m's tau grid
    const float lbm = lbL[mi], ubm = ubL[mi];
    int i0a[12]; float wa[12];
    #pragma unroll
    for (int k12 = 0; k12 < 12; k12++) {
      int k = kg + 8*k12;
      float tau = lbm + (ubm - lbm) * (float)k * (1.0f/95.0f);
      float x = fminf(fmaxf(tau / T2, 0.f), 1.f) * (float)(N2-1);
      int i0 = (int)x; i0 = max(0, min(i0, N2-2));
      i0a[k12] = i0; wa[k12] = x - (float)i0;
    }
    for (int d4 = 0; d4 < 32; d4++) {
      float4 s1v = s1L4[mi*33 + d4];
      #pragma unroll
      for (int k12 = 0; k12 < 12; k12++) {
        float4 f0 = s2f4[(size_t)i0a[k12]*32 + d4];
        float4 f1 = s2f4[(size_t)(i0a[k12]+1)*32 + d4];
        float w = wa[k12];
        float ax = f0.x + (f1.x - f0.x)*w, ay = f0.y + (f1.y - f0.y)*w;
        float az = f0.z + (f1.z - f0.z)*w, aw = f0.w + (f1.w - f0.w)*w;
        float dx = s1v.x - ax, dy = s1v.y - ay, dz = s1v.z - az, dw = s1v.w - aw;
        acc[k12] += dx*dx + dy*dy + dz*dz + dw*dw;
      }
    }
  }
  {
    const float wts = wtsL[mi];
    const float lbm = lbL[mi], ubm = ubL[mi];
    #pragma unroll
    for (int k12 = 0; k12 < 12; k12++) {
      int k = kg + 8*k12;
      float nodev = acc[k12] * wts;
      float tau = lbm + (ubm - lbm) * (float)k * (1.0f/95.0f);
      if (m == 0)    nodev += BARRIER * tau * tau;
      if (m == MW-1) { float dd = tau - T2; nodev += BARRIER * dd * dd; }
      ndt[mi*99 + k] = nodev;
    }
  }
  __syncthreads();
  float* nodeP = ws + WS_NODE + ((size_t)b*MW + mb*32)*KD;
  for (int idx = t; idx < 32*KD; idx += 256) {
    int mi2 = idx / KD, kv = idx - mi2*KD;
    nodeP[idx] = ndt[mi2*99 + kv];
  }
  if (t < 32) {
    float mn = 3e38f;
    for (int k = 0; k < KD; k++) mn = fminf(mn, ndt[t*99 + k]);
    ws[WS_NDMIN + b*MW + mb*32 + t] = mn;
  }
}

// ---------------- K2: banded log-domain DP ----------------
// 128 threads per (b,dir). Thread t<96 owns state k=t. Rigorous band pruning:
// term j negligible if e(k,j) > emin_k + spread(sA) + 8.7 (e^-87 underflow).
// Blo = provable running lower bound on min(sA); per-step check with per-thread
// exact-fallback keeps arbitrary inputs correct.
__global__ __launch_bounds__(128) void k2_dp(const float* __restrict__ tw,
                                             const float* __restrict__ glb_lb,
                                             const float* __restrict__ glb_ub,
                                             const float* __restrict__ reg_wt,
                                             const float* __restrict__ gubp,
                                             float* __restrict__ ws) {
  const int dir = blockIdx.x;   // 0 fwd, 1 bwd
  const int b = blockIdx.y;
  const int t = threadIdx.x;    // 0..127
  const bool act = t < KD;
  const int k = act ? t : (KD-1);
  __shared__ float lbw[MW], ubw[MW], twv[MW];
  __shared__ float sAb[2][128];
  __shared__ float eL[KD*97];
  __shared__ float sc[KD];
  __shared__ int viof[2];
  const float T2 = ws[WS_T2MAX + b];
  for (int i = t; i < MW; i += 128) {
    lbw[i] = glb_lb[b*MW+i] * T2;
    ubw[i] = glb_ub[b*MW+i] * T2;
    twv[i] = tw[b*MW+i];
  }
  const float r = reg_wt[b];
  const float gub = gubp[b];
  const float frk = (float)k * (1.0f/95.0f);
  const float* __restrict__ nodeP = ws + WS_NODE + (size_t)b*MW*KD;
  const float* __restrict__ ndminP = ws + WS_NDMIN + b*MW;
  float* __restrict__ outP = ws + ((dir==0)?WS_ABUF:WS_BBUF) + (size_t)b*MW*KD;

  float cL1 = __int_as_float(0x7fc00000);
  float cU1 = cL1, cL2 = cL1, cU2 = cL1, cdt = cL1;
  int   lo = 0, len = KD;
  float eout = 3e38f, Blo = -3e38f, eminmin = 0.f;

  if (t == 0) { viof[0] = -99; viof[1] = -99; }
  {
    float v0 = nodeP[(size_t)(dir ? (MW-1) : 0)*KD + k];
    if (act) {
      sAb[0][k] = v0;
      if (dir == 0) outP[k] = v0;
      else          outP[(size_t)(MW-1)*KD + k] = 0.0f;
    }
  }
  __syncthreads();

  for (int step = 0; step < MW-1; step++) {
    const int rd = step & 1, wr = rd ^ 1;
    const int i  = (dir==0) ? step : (MW-2-step);
    const int m1 = i, m2 = i+1;
    const int mnode = (dir==0) ? m2 : m1;
    const float L1 = lbw[m1], U1 = ubw[m1], L2 = lbw[m2], U2 = ubw[m2];
    const float dt = twv[m2] - twv[m1];
    const float nd   = nodeP[(size_t)mnode*KD + k];   // early global load
    const float ndmn = ndminP[mnode];
    const bool kc  = !(feq(L1,cL1) && feq(U1,cU1) && feq(L2,cL2) && feq(U2,cU2) && feq(dt,cdt));
    const bool flg = (viof[wr] == step-1);
    if (kc || flg) {        // block-uniform
      cL1=L1; cU1=U1; cL2=L2; cU2=U2; cdt=dt;
      float mnS = 3e38f, mxS = -3e38f;
      for (int j = 0; j < KD; j++) { float v = sAb[rd][j]; mnS = fminf(mnS,v); mxS = fmaxf(mxS,v); }
      const float invdt = 1.0f/dt, rdt = r*dt;
      const float mytau = dir ? (L1+(U1-L1)*frk) : (L2+(U2-L2)*frk);
      float emin = 3e38f;
      for (int j = 0; j < KD; j++) {
        float frj = (float)j*(1.0f/95.0f);
        float oth = dir ? (L2+(U2-L2)*frj) : (L1+(U1-L1)*frj);
        float slope = (dir ? (oth-mytau) : (mytau-oth)) * invdt;
        float s1v = slope - 1.0f;
        float ng = fminf(slope, 0.f);
        float ov = fmaxf(slope - gub, 0.f);
        float e = rdt*s1v*s1v + BARRIER*(ng*ng + ov*ov);
        eL[k*97 + j] = e; emin = fminf(emin, e);
      }
      const float thr = emin + (mxS - mnS) + (MARGIN + 9.0f);
      int lo_ = KD, hi_ = -1;
      for (int j = 0; j < KD; j++) {
        float e = eL[k*97 + j];
        if (e <= thr) { hi_ = j; if (lo_ == KD) lo_ = j; }
      }
      float eo = 3e38f;
      for (int j = 0; j < lo_; j++)    eo = fminf(eo, eL[k*97 + j]);
      for (int j = hi_+1; j < KD; j++) eo = fminf(eo, eL[k*97 + j]);
      lo = lo_; len = hi_ - lo_ + 1; eout = eo;
      sc[k] = emin;
      Blo = mnS;
      __syncthreads();
      float emm = 3e38f;
      for (int j = 0; j < KD; j++) emm = fminf(emm, sc[j]);
      eminmin = emm;
    }
    // banded softmin
    float mn = 3e38f;
    for (int jj = 0; jj < len; jj++) {
      float x = sAb[rd][lo+jj] + eL[k*97 + lo+jj];
      mn = fminf(mn, x);
    }
    float sum = 0.f;
    for (int jj = 0; jj < len; jj++) {
      float x = sAb[rd][lo+jj] + eL[k*97 + lo+jj];
      sum += __expf((mn - x) * INVG);
    }
    // rigor check: excluded terms provably < e^-87?
    if (Blo + eout - mn < 8.7f) {
      mn = 3e38f;
      for (int j = 0; j < KD; j++) { float x = sAb[rd][j] + eL[k*97+j]; mn = fminf(mn, x); }
      sum = 0.f;
      for (int j = 0; j < KD; j++) { float x = sAb[rd][j] + eL[k*97+j]; sum += __expf((mn-x)*INVG); }
      viof[rd] = step;   // request band recompute next step
    }
    const float sval = mn - GAM * __logf(sum);
    const float v = nd + sval;          // fwd: alpha_m2 ; bwd: C_m1 = beta+node
    if (act) {
      sAb[wr][k] = v;
      outP[(size_t)mnode*KD + k] = dir ? sval : v;
    }
    Blo += eminmin + ndmn - 0.4575f;    // >= gamma*ln(96) + slack
    __syncthreads();
  }
}

// ---------------- K3: softmax readout ----------------
__global__ __launch_bounds__(256) void k3_final(const float* __restrict__ glb_lb,
                                                const float* __restrict__ glb_ub,
                                                const float* __restrict__ ws,
                                                float* __restrict__ out) {
  const int wv = threadIdx.x >> 6;
  const int lane = threadIdx.x & 63;
  const int gw = blockIdx.x * 4 + wv;      // b*256+m
  const int b = gw >> 8, m = gw & 255;
  const float T2 = ws[WS_T2MAX + b];
  const float lb = glb_lb[b*MW+m] * T2;
  const float ub = glb_ub[b*MW+m] * T2;
  const float* __restrict__ Ab = ws + WS_ABUF + (size_t)gw*KD;
  const float* __restrict__ Bb = ws + WS_BBUF + (size_t)gw*KD;
  float s0 = Ab[lane] + Bb[lane];
  float s1 = 1e30f;
  if (lane < KD - 64) s1 = Ab[lane+64] + Bb[lane+64];
  float mn = fminf(s0, s1);
  #pragma unroll
  for (int o = 32; o; o >>= 1) mn = fminf(mn, __shfl_xor(mn, o));
  const float tau0 = lb + (ub-lb) * (float)lane * (1.0f/95.0f);
  const float tau1 = lb + (ub-lb) * (float)(lane+64) * (1.0f/95.0f);
  float w0 = __expf((mn - s0) * INVG);
  float w1 = __expf((mn - s1) * INVG);
  float num = w0*tau0 + w1*tau1;
  float den = w0 + w1;
  #pragma unroll
  for (int o = 32; o; o >>= 1) {
    num += __shfl_down(num, o);
    den += __shfl_down(den, o);
  }
  if (lane == 0) out[gw] = num / den;
}

extern "C" void kernel_launch(void* const* d_in, const int* in_sizes, int n_in,
                              void* d_out, int out_size, void* d_ws, size_t ws_size,
                              hipStream_t stream) {
  const float* s1f    = (const float*)d_in[0];
  const float* s2f    = (const float*)d_in[1];
  const float* regw   = (const float*)d_in[2];
  const float* glb_lb = (const float*)d_in[3];
  const float* glb_ub = (const float*)d_in[4];
  const float* gubp   = (const float*)d_in[5];
  const float* t1     = (const float*)d_in[6];
  const float* t2     = (const float*)d_in[7];
  const float* twp    = (const float*)d_in[8];
  float* ws  = (float*)d_ws;
  float* out = (float*)d_out;

  k0_rowmax<<<NB, 256, 0, stream>>>(t1, t2, ws);
  dim3 g1(8, NB);
  k1_node<<<g1, 256, 0, stream>>>(s1f, s2f, twp, glb_lb, glb_ub, ws);
  dim3 g2(2, NB);
  k2_dp<<<g2, 128, 0, stream>>>(twp, glb_lb, glb_ub, regw, gubp, ws);
  k3_final<<<MW*NB/4, 256, 0, stream>>>(glb_lb, glb_ub, ws, out);
}

// Round 5
// 263.998 us; speedup vs baseline: 1.9040x; 1.3640x over previous
//
#include <hip/hip_runtime.h>

#define NB 32
#define N1 512
#define N2 512
#define DF 128
#define MW 256
#define KD 96
#define INVG 10.0f
#define GAM 0.1f
#define BARRIER 10000.0f

// ws layout (floats)
#define WS_T1MAX 0
#define WS_T2MAX (NB)
#define WS_NDMIN (2*NB)
#define WS_NODE  (WS_NDMIN + NB*MW)
#define WS_ABUF  (WS_NODE + NB*MW*KD)
#define WS_BBUF  (WS_ABUF + NB*MW*KD)

__device__ __forceinline__ bool feq(float a, float b) {
  return fabsf(a - b) <= 1e-4f * fmaxf(fabsf(a), fabsf(b)) + 1e-12f;
}

// ---------------- K0: per-b max of t1, t2 ----------------
__global__ __launch_bounds__(256) void k0_rowmax(const float* __restrict__ t1,
                                                 const float* __restrict__ t2,
                                                 float* __restrict__ ws) {
  int b = blockIdx.x;
  int t = threadIdx.x;
  float m1 = -1e30f, m2 = -1e30f;
  for (int i = t; i < N1; i += 256) m1 = fmaxf(m1, t1[b*N1+i]);
  for (int i = t; i < N2; i += 256) m2 = fmaxf(m2, t2[b*N2+i]);
  __shared__ float sm1[4], sm2[4];
  #pragma unroll
  for (int o = 32; o; o >>= 1) {
    m1 = fmaxf(m1, __shfl_down(m1, o));
    m2 = fmaxf(m2, __shfl_down(m2, o));
  }
  int wv = t >> 6;
  if ((t & 63) == 0) { sm1[wv] = m1; sm2[wv] = m2; }
  __syncthreads();
  if (t == 0) {
    ws[WS_T1MAX + b] = fmaxf(fmaxf(sm1[0], sm1[1]), fmaxf(sm1[2], sm1[3]));
    ws[WS_T2MAX + b] = fmaxf(fmaxf(sm2[0], sm2[1]), fmaxf(sm2[2], sm2[3]));
  }
}

// ---------------- K1: node costs (tiled distance matrix) ----------------
__global__ __launch_bounds__(256) void k1_node(const float* __restrict__ s1f,
                                               const float* __restrict__ s2f,
                                               const float* __restrict__ tw,
                                               const float* __restrict__ glb_lb,
                                               const float* __restrict__ glb_ub,
                                               float* __restrict__ ws) {
  const int mb = blockIdx.x;
  const int b  = blockIdx.y;
  const int t  = threadIdx.x;
  __shared__ float s1L[32*132];
  __shared__ float s2L[96*132];
  __shared__ float ndt[32*99];
  __shared__ float wtsL[32], lbL[32], ubL[32];
  __shared__ int   matchL[32];
  const float T1 = ws[WS_T1MAX + b];
  const float T2 = ws[WS_T2MAX + b];
  const float lb0 = glb_lb[b*MW] * T2;
  const float ub0 = glb_ub[b*MW] * T2;
  float4* s1L4 = (float4*)s1L;
  float4* s2L4 = (float4*)s2L;
  const float4* s1f4 = (const float4*)(s1f + (size_t)b*N1*DF);
  const float4* s2f4 = (const float4*)(s2f + (size_t)b*N2*DF);

  {
    const int d32 = t & 31;
    const int k8  = t >> 5;
    for (int kk = 0; kk < 12; kk++) {
      int k = k8 + 8*kk;
      float tau = lb0 + (ub0 - lb0) * (float)k * (1.0f/95.0f);
      float x = fminf(fmaxf(tau / T2, 0.f), 1.f) * (float)(N2-1);
      int i0 = (int)x; i0 = max(0, min(i0, N2-2));
      float w = x - (float)i0;
      float4 f0 = s2f4[(size_t)i0*32 + d32];
      float4 f1 = s2f4[(size_t)(i0+1)*32 + d32];
      float4 r;
      r.x = f0.x + (f1.x - f0.x)*w; r.y = f0.y + (f1.y - f0.y)*w;
      r.z = f0.z + (f1.z - f0.z)*w; r.w = f0.w + (f1.w - f0.w)*w;
      s2L4[k*33 + d32] = r;
    }
  }
  {
    const int mi = t >> 3, q = t & 7;
    const int m = mb*32 + mi;
    float twm = tw[b*MW + m];
    float x = fminf(fmaxf(twm / T1, 0.f), 1.f) * (float)(N1-1);
    int i0 = (int)x; i0 = max(0, min(i0, N1-2));
    float w = x - (float)i0;
    #pragma unroll
    for (int j = 0; j < 4; j++) {
      int d4 = q + 8*j;
      float4 f0 = s1f4[(size_t)i0*32 + d4];
      float4 f1 = s1f4[(size_t)(i0+1)*32 + d4];
      float4 r;
      r.x = f0.x + (f1.x - f0.x)*w; r.y = f0.y + (f1.y - f0.y)*w;
      r.z = f0.z + (f1.z - f0.z)*w; r.w = f0.w + (f1.w - f0.w)*w;
      s1L4[mi*33 + d4] = r;
    }
  }
  if (t < 32) {
    int m = mb*32 + t, g = b*MW + m;
    float twm = tw[g];
    float prev = (m > 0) ? tw[g-1] : twm;
    float next = (m < MW-1) ? tw[g+1] : twm;
    wtsL[t] = 0.5f*(next - prev);
    float lbm = glb_lb[g]*T2, ubm = glb_ub[g]*T2;
    lbL[t] = lbm; ubL[t] = ubm;
    matchL[t] = (feq(lbm, lb0) && feq(ubm, ub0)) ? 1 : 0;
  }
  __syncthreads();

  const int mi = t >> 3, kg = t & 7;
  const int m = mb*32 + mi;
  float acc[12];
  #pragma unroll
  for (int i = 0; i < 12; i++) acc[i] = 0.f;
  if (matchL[mi]) {
    for (int d4 = 0; d4 < 32; d4++) {
      float4 s1v = s1L4[mi*33 + d4];
      #pragma unroll
      for (int k12 = 0; k12 < 12; k12++) {
        int k = kg + 8*k12;
        float4 s2v = s2L4[k*33 + d4];
        float dx = s1v.x - s2v.x, dy = s1v.y - s2v.y;
        float dz = s1v.z - s2v.z, dw = s1v.w - s2v.w;
        acc[k12] += dx*dx + dy*dy + dz*dz + dw*dw;
      }
    }
  } else {
    const float lbm = lbL[mi], ubm = ubL[mi];
    int i0a[12]; float wa[12];
    #pragma unroll
    for (int k12 = 0; k12 < 12; k12++) {
      int k = kg + 8*k12;
      float tau = lbm + (ubm - lbm) * (float)k * (1.0f/95.0f);
      float x = fminf(fmaxf(tau / T2, 0.f), 1.f) * (float)(N2-1);
      int i0 = (int)x; i0 = max(0, min(i0, N2-2));
      i0a[k12] = i0; wa[k12] = x - (float)i0;
    }
    for (int d4 = 0; d4 < 32; d4++) {
      float4 s1v = s1L4[mi*33 + d4];
      #pragma unroll
      for (int k12 = 0; k12 < 12; k12++) {
        float4 f0 = s2f4[(size_t)i0a[k12]*32 + d4];
        float4 f1 = s2f4[(size_t)(i0a[k12]+1)*32 + d4];
        float w = wa[k12];
        float ax = f0.x + (f1.x - f0.x)*w, ay = f0.y + (f1.y - f0.y)*w;
        float az = f0.z + (f1.z - f0.z)*w, aw = f0.w + (f1.w - f0.w)*w;
        float dx = s1v.x - ax, dy = s1v.y - ay, dz = s1v.z - az, dw = s1v.w - aw;
        acc[k12] += dx*dx + dy*dy + dz*dz + dw*dw;
      }
    }
  }
  {
    const float wts = wtsL[mi];
    const float lbm = lbL[mi], ubm = ubL[mi];
    #pragma unroll
    for (int k12 = 0; k12 < 12; k12++) {
      int k = kg + 8*k12;
      float nodev = acc[k12] * wts;
      float tau = lbm + (ubm - lbm) * (float)k * (1.0f/95.0f);
      if (m == 0)    nodev += BARRIER * tau * tau;
      if (m == MW-1) { float dd = tau - T2; nodev += BARRIER * dd * dd; }
      ndt[mi*99 + k] = nodev;
    }
  }
  __syncthreads();
  float* nodeP = ws + WS_NODE + ((size_t)b*MW + mb*32)*KD;
  for (int idx = t; idx < 32*KD; idx += 256) {
    int mi2 = idx / KD, kv = idx - mi2*KD;
    nodeP[idx] = ndt[mi2*99 + kv];
  }
  if (t < 32) {
    float mn = 3e38f;
    for (int k = 0; k < KD; k++) mn = fminf(mn, ndt[t*99 + k]);
    ws[WS_NDMIN + b*MW + mb*32 + t] = mn;
  }
}

// ---------------- K2: single-wave register DP, 2 states/lane ----------------
// One block per b, 128 threads = wave0 fwd + wave1 bwd. Lane L<48 owns states
// k0=2L, k1=2L+1. Band fixed to {k-1,k,k+1}; per-step rigor check
// (Blo + eout - mn >= 8.7 -> excluded terms underflow exactly) with exact
// 96-term fallback. NaN containment: band terms clamped via fminf(.,3e38)
// (IEEE minNum maps NaN/inf -> 3e38), inactive lanes pinned to 3e38 so
// shuffles from lane 48 never deliver NaN to lane 47.
__global__ __launch_bounds__(128) void k2_dp(const float* __restrict__ tw,
                                             const float* __restrict__ glb_lb,
                                             const float* __restrict__ glb_ub,
                                             const float* __restrict__ reg_wt,
                                             const float* __restrict__ gubp,
                                             float* __restrict__ ws) {
  const int b = blockIdx.x;
  const int t = threadIdx.x;
  const int dir = t >> 6;        // wave0 fwd, wave1 bwd
  const int lane = t & 63;
  const bool act = lane < 48;
  __shared__ float ndL[MW*KD];   // 96 KB
  __shared__ float ndmL[MW];
  __shared__ float lbw[MW], ubw[MW], twv[MW];
  __shared__ float mir[2][KD];
  const float T2 = ws[WS_T2MAX + b];
  {
    const float4* np4 = (const float4*)(ws + WS_NODE + (size_t)b*MW*KD);
    float4* nl4 = (float4*)ndL;
    #pragma unroll
    for (int it = 0; it < (MW*KD/4)/128; it++)
      nl4[t + 128*it] = np4[t + 128*it];
    for (int i2 = t; i2 < MW; i2 += 128) {
      ndmL[i2] = ws[WS_NDMIN + b*MW + i2];
      lbw[i2] = glb_lb[b*MW+i2]*T2;
      ubw[i2] = glb_ub[b*MW+i2]*T2;
      twv[i2] = tw[b*MW+i2];
    }
  }
  const float r = reg_wt[b];
  const float gub = gubp[b];
  const int k0i = 2*lane, k1i = 2*lane+1;
  const float frk0 = (float)k0i*(1.f/95.f), frk1 = (float)k1i*(1.f/95.f);
  float* __restrict__ outP = ws + (dir ? WS_BBUF : WS_ABUF) + (size_t)b*MW*KD;
  __syncthreads();

  float a0 = 3e38f, a1 = 3e38f;
  {
    const int m0 = dir ? (MW-1) : 0;
    if (act) {
      a0 = ndL[m0*KD + k0i]; a1 = ndL[m0*KD + k1i];
      mir[dir][k0i] = a0; mir[dir][k1i] = a1;
      float2 o; o.x = dir ? 0.f : a0; o.y = dir ? 0.f : a1;
      *(float2*)&outP[(size_t)m0*KD + k0i] = o;
    }
  }
  float Blo;
  {
    float bl = act ? fminf(a0, a1) : 3e38f;
    #pragma unroll
    for (int o = 1; o < 64; o <<= 1) bl = fminf(bl, __shfl_xor(bl, o));
    Blo = bl;
  }
  float e00=3e38f,e0m=3e38f,e0p=3e38f,e10=3e38f,e1m=3e38f,e1p=3e38f;
  float eo0=3e38f, eo1=3e38f, eminmin=0.f;
  float cL1=__int_as_float(0x7fc00000), cU1=cL1, cL2=cL1, cU2=cL1, cdt=cL1;

  // prefetch step-0
  float pL1, pU1, pL2, pU2, pt1, pt2, pnd0=0.f, pnd1=0.f, pndm;
  {
    const int i0_ = dir ? (MW-2) : 0;
    pL1=lbw[i0_]; pU1=ubw[i0_]; pL2=lbw[i0_+1]; pU2=ubw[i0_+1];
    pt1=twv[i0_]; pt2=twv[i0_+1];
    const int mn_ = dir ? i0_ : (i0_+1);
    if (act) { float2 v = *(const float2*)&ndL[mn_*KD + k0i]; pnd0=v.x; pnd1=v.y; }
    pndm = ndmL[mn_];
  }

  for (int step = 0; step < MW-1; step++) {
    const float L1=pL1, U1=pU1, L2=pL2, U2=pU2;
    const float dt = pt2 - pt1;
    const float nd0=pnd0, nd1=pnd1, ndmn=pndm;
    {   // prefetch next step
      const int sn = (step+1 < MW-1) ? (step+1) : step;
      const int in_ = dir ? (MW-2-sn) : sn;
      pL1=lbw[in_]; pU1=ubw[in_]; pL2=lbw[in_+1]; pU2=ubw[in_+1];
      pt1=twv[in_]; pt2=twv[in_+1];
      const int mn_ = dir ? in_ : (in_+1);
      if (act) { float2 v = *(const float2*)&ndL[mn_*KD + k0i]; pnd0=v.x; pnd1=v.y; }
      pndm = ndmL[mn_];
    }
    const bool kc = !(feq(L1,cL1)&&feq(U1,cU1)&&feq(L2,cL2)&&feq(U2,cU2)&&feq(dt,cdt));
    if (kc) {
      cL1=L1; cU1=U1; cL2=L2; cU2=U2; cdt=dt;
      float bl = act ? fminf(mir[dir][k0i], mir[dir][k1i]) : 3e38f;
      #pragma unroll
      for (int o = 1; o < 64; o <<= 1) bl = fminf(bl, __shfl_xor(bl, o));
      Blo = bl;
      const float invdt = 1.f/dt, rdt = r*dt;
      const float my0 = dir ? (L1+(U1-L1)*frk0) : (L2+(U2-L2)*frk0);
      const float my1 = dir ? (L1+(U1-L1)*frk1) : (L2+(U2-L2)*frk1);
      e00=3e38f; e0m=3e38f; e0p=3e38f; e10=3e38f; e1m=3e38f; e1p=3e38f;
      eo0=3e38f; eo1=3e38f;
      float emn = 3e38f;
      for (int j = 0; j < KD; j++) {
        const float frj = (float)j*(1.f/95.f);
        const float oth = dir ? (L2+(U2-L2)*frj) : (L1+(U1-L1)*frj);
        const float sl0 = (dir ? (oth-my0) : (my0-oth))*invdt;
        const float sl1 = (dir ? (oth-my1) : (my1-oth))*invdt;
        float d0=sl0-1.f, g0=fminf(sl0,0.f), v0=fmaxf(sl0-gub,0.f);
        float ej0 = rdt*d0*d0 + BARRIER*(g0*g0+v0*v0);
        float d1=sl1-1.f, g1=fminf(sl1,0.f), v1=fmaxf(sl1-gub,0.f);
        float ej1 = rdt*d1*d1 + BARRIER*(g1*g1+v1*v1);
        emn = fminf(emn, fminf(ej0, ej1));
        if      (j == k0i-1) e0m = ej0;
        else if (j == k0i)   e00 = ej0;
        else if (j == k0i+1) e0p = ej0;
        else                 eo0 = fminf(eo0, ej0);
        if      (j == k1i-1) e1m = ej1;
        else if (j == k1i)   e10 = ej1;
        else if (j == k1i+1) e1p = ej1;
        else                 eo1 = fminf(eo1, ej1);
      }
      if (!act) emn = 3e38f;
      #pragma unroll
      for (int o = 1; o < 64; o <<= 1) emn = fminf(emn, __shfl_xor(emn, o));
      eminmin = emn;
    }
    const float a1p = __shfl_up(a1, 1);     // state k0-1
    const float a0n = __shfl_down(a0, 1);   // state k1+1
    // fminf clamp: maps inf/NaN operands to 3e38 (IEEE minNum) -> exp term 0
    const float x0m = fminf(a1p + e0m, 3e38f);
    const float x00 = fminf(a0  + e00, 3e38f);
    const float x0p = fminf(a1  + e0p, 3e38f);
    const float x1m = fminf(a0  + e1m, 3e38f);
    const float x10 = fminf(a1  + e10, 3e38f);
    const float x1p = fminf(a0n + e1p, 3e38f);
    float mn0 = fminf(fminf(x0m, x00), x0p);
    float mn1 = fminf(fminf(x1m, x10), x1p);
    float sum0 = __expf((mn0-x0m)*INVG) + __expf((mn0-x00)*INVG) + __expf((mn0-x0p)*INVG);
    float sum1 = __expf((mn1-x1m)*INVG) + __expf((mn1-x10)*INVG) + __expf((mn1-x1p)*INVG);
    const bool bad = act && ((Blo + eo0 - mn0 < 8.7f) || (Blo + eo1 - mn1 < 8.7f));
    if (__any((int)bad)) {
      // exact fallback: full 96-term softmin from LDS mirror, e recomputed
      const float invdt = 1.f/dt, rdt = r*dt;
      const float my0 = dir ? (L1+(U1-L1)*frk0) : (L2+(U2-L2)*frk0);
      const float my1 = dir ? (L1+(U1-L1)*frk1) : (L2+(U2-L2)*frk1);
      mn0 = 3e38f; mn1 = 3e38f;
      for (int j = 0; j < KD; j++) {
        const float sj = mir[dir][j];
        const float frj = (float)j*(1.f/95.f);
        const float oth = dir ? (L2+(U2-L2)*frj) : (L1+(U1-L1)*frj);
        const float sl0 = (dir ? (oth-my0) : (my0-oth))*invdt;
        const float sl1 = (dir ? (oth-my1) : (my1-oth))*invdt;
        float d0=sl0-1.f, g0=fminf(sl0,0.f), v0=fmaxf(sl0-gub,0.f);
        float ej0 = rdt*d0*d0 + BARRIER*(g0*g0+v0*v0);
        float d1=sl1-1.f, g1=fminf(sl1,0.f), v1=fmaxf(sl1-gub,0.f);
        float ej1 = rdt*d1*d1 + BARRIER*(g1*g1+v1*v1);
        mn0 = fminf(mn0, fminf(sj + ej0, 3e38f));
        mn1 = fminf(mn1, fminf(sj + ej1, 3e38f));
      }
      sum0 = 0.f; sum1 = 0.f;
      for (int j = 0; j < KD; j++) {
        const float sj = mir[dir][j];
        const float frj = (float)j*(1.f/95.f);
        const float oth = dir ? (L2+(U2-L2)*frj) : (L1+(U1-L1)*frj);
        const float sl0 = (dir ? (oth-my0) : (my0-oth))*invdt;
        const float sl1 = (dir ? (oth-my1) : (my1-oth))*invdt;
        float d0=sl0-1.f, g0=fminf(sl0,0.f), v0=fmaxf(sl0-gub,0.f);
        float ej0 = rdt*d0*d0 + BARRIER*(g0*g0+v0*v0);
        float d1=sl1-1.f, g1=fminf(sl1,0.f), v1=fmaxf(sl1-gub,0.f);
        float ej1 = rdt*d1*d1 + BARRIER*(g1*g1+v1*v1);
        sum0 += __expf((mn0 - fminf(sj + ej0, 3e38f))*INVG);
        sum1 += __expf((mn1 - fminf(sj + ej1, 3e38f))*INVG);
      }
    }
    const float sv0 = mn0 - GAM*__logf(sum0);
    const float sv1 = mn1 - GAM*__logf(sum1);
    const float na0 = nd0 + sv0, na1 = nd1 + sv1;
    const int ic = dir ? (MW-2-step) : step;
    const int mnode = dir ? ic : (ic+1);
    if (act) {
      mir[dir][k0i] = na0; mir[dir][k1i] = na1;
      float2 o; o.x = dir ? sv0 : na0; o.y = dir ? sv1 : na1;
      *(float2*)&outP[(size_t)mnode*KD + k0i] = o;
    }
    // pin inactive lanes so shuffles never deliver NaN/garbage to lane 47
    a0 = act ? na0 : 3e38f;
    a1 = act ? na1 : 3e38f;
    Blo += eminmin + ndmn - 0.4575f;   // >= gamma*ln(96)
  }
}

// ---------------- K3: softmax readout ----------------
__global__ __launch_bounds__(256) void k3_final(const float* __restrict__ glb_lb,
                                                const float* __restrict__ glb_ub,
                                                const float* __restrict__ ws,
                                                float* __restrict__ out) {
  const int wv = threadIdx.x >> 6;
  const int lane = threadIdx.x & 63;
  const int gw = blockIdx.x * 4 + wv;      // b*256+m
  const int b = gw >> 8, m = gw & 255;
  const float T2 = ws[WS_T2MAX + b];
  const float lb = glb_lb[b*MW+m] * T2;
  const float ub = glb_ub[b*MW+m] * T2;
  const float* __restrict__ Ab = ws + WS_ABUF + (size_t)gw*KD;
  const float* __restrict__ Bb = ws + WS_BBUF + (size_t)gw*KD;
  float s0 = Ab[lane] + Bb[lane];
  float s1 = 1e30f;
  if (lane < KD - 64) s1 = Ab[lane+64] + Bb[lane+64];
  float mn = fminf(s0, s1);
  #pragma unroll
  for (int o = 32; o; o >>= 1) mn = fminf(mn, __shfl_xor(mn, o));
  const float tau0 = lb + (ub-lb) * (float)lane * (1.0f/95.0f);
  const float tau1 = lb + (ub-lb) * (float)(lane+64) * (1.0f/95.0f);
  float w0 = __expf((mn - s0) * INVG);
  float w1 = __expf((mn - s1) * INVG);
  float num = w0*tau0 + w1*tau1;
  float den = w0 + w1;
  #pragma unroll
  for (int o = 32; o; o >>= 1) {
    num += __shfl_down(num, o);
    den += __shfl_down(den, o);
  }
  if (lane == 0) out[gw] = num / den;
}

extern "C" void kernel_launch(void* const* d_in, const int* in_sizes, int n_in,
                              void* d_out, int out_size, void* d_ws, size_t ws_size,
                              hipStream_t stream) {
  const float* s1f    = (const float*)d_in[0];
  const float* s2f    = (const float*)d_in[1];
  const float* regw   = (const float*)d_in[2];
  const float* glb_lb = (const float*)d_in[3];
  const float* glb_ub = (const float*)d_in[4];
  const float* gubp   = (const float*)d_in[5];
  const float* t1     = (const float*)d_in[6];
  const float* t2     = (const float*)d_in[7];
  const float* twp    = (const float*)d_in[8];
  float* ws  = (float*)d_ws;
  float* out = (float*)d_out;

  k0_rowmax<<<NB, 256, 0, stream>>>(t1, t2, ws);
  dim3 g1(8, NB);
  k1_node<<<g1, 256, 0, stream>>>(s1f, s2f, twp, glb_lb, glb_ub, ws);
  k2_dp<<<NB, 128, 0, stream>>>(twp, glb_lb, glb_ub, regw, gubp, ws);
  k3_final<<<MW*NB/4, 256, 0, stream>>>(glb_lb, glb_ub, ws, out);
}

// Round 6
// 116.344 us; speedup vs baseline: 4.3205x; 2.2691x over previous
//
#include <hip/hip_runtime.h>

#define NB 32
#define N1 512
#define N2 512
#define DF 128
#define MW 256
#define KD 96
#define INVG 10.0f
#define GAM 0.1f
#define BARRIER 10000.0f

// ws layout (floats)
#define WS_T1MAX 0
#define WS_T2MAX (NB)
#define WS_NDMIN (2*NB)
#define WS_FLAG  (WS_NDMIN + NB*MW)
#define WS_LOGIT (WS_FLAG + NB)
#define WS_NODE  (WS_LOGIT + NB*KD)
#define WS_ABUF  (WS_NODE + NB*MW*KD)
#define WS_BBUF  (WS_ABUF + NB*MW*KD)

__device__ __forceinline__ bool feq(float a, float b) {
  return fabsf(a - b) <= 1e-4f * fmaxf(fabsf(a), fabsf(b)) + 1e-12f;
}

__device__ __forceinline__ float edgec(float s, float rdtv, float gub) {
  float d = s - 1.0f, ng = fminf(s, 0.f), ov = fmaxf(s - gub, 0.f);
  return rdtv*d*d + BARRIER*(ng*ng + ov*ov);
}

// ---------------- K0: per-b max of t1, t2 ----------------
__global__ __launch_bounds__(256) void k0_rowmax(const float* __restrict__ t1,
                                                 const float* __restrict__ t2,
                                                 float* __restrict__ ws) {
  int b = blockIdx.x;
  int t = threadIdx.x;
  float m1 = -1e30f, m2 = -1e30f;
  for (int i = t; i < N1; i += 256) m1 = fmaxf(m1, t1[b*N1+i]);
  for (int i = t; i < N2; i += 256) m2 = fmaxf(m2, t2[b*N2+i]);
  __shared__ float sm1[4], sm2[4];
  #pragma unroll
  for (int o = 32; o; o >>= 1) {
    m1 = fmaxf(m1, __shfl_down(m1, o));
    m2 = fmaxf(m2, __shfl_down(m2, o));
  }
  int wv = t >> 6;
  if ((t & 63) == 0) { sm1[wv] = m1; sm2[wv] = m2; }
  __syncthreads();
  if (t == 0) {
    ws[WS_T1MAX + b] = fmaxf(fmaxf(sm1[0], sm1[1]), fmaxf(sm1[2], sm1[3]));
    ws[WS_T2MAX + b] = fmaxf(fmaxf(sm2[0], sm2[1]), fmaxf(sm2[2], sm2[3]));
  }
}

// ---------------- K1: node costs (tiled distance matrix) ----------------
__global__ __launch_bounds__(256) void k1_node(const float* __restrict__ s1f,
                                               const float* __restrict__ s2f,
                                               const float* __restrict__ tw,
                                               const float* __restrict__ glb_lb,
                                               const float* __restrict__ glb_ub,
                                               float* __restrict__ ws) {
  const int mb = blockIdx.x;
  const int b  = blockIdx.y;
  const int t  = threadIdx.x;
  __shared__ float s1L[32*132];
  __shared__ float s2L[96*132];
  __shared__ float ndt[32*99];
  __shared__ float wtsL[32], lbL[32], ubL[32];
  __shared__ int   matchL[32];
  const float T1 = ws[WS_T1MAX + b];
  const float T2 = ws[WS_T2MAX + b];
  const float lb0 = glb_lb[b*MW] * T2;
  const float ub0 = glb_ub[b*MW] * T2;
  float4* s1L4 = (float4*)s1L;
  float4* s2L4 = (float4*)s2L;
  const float4* s1f4 = (const float4*)(s1f + (size_t)b*N1*DF);
  const float4* s2f4 = (const float4*)(s2f + (size_t)b*N2*DF);

  {
    const int d32 = t & 31;
    const int k8  = t >> 5;
    for (int kk = 0; kk < 12; kk++) {
      int k = k8 + 8*kk;
      float tau = lb0 + (ub0 - lb0) * (float)k * (1.0f/95.0f);
      float x = fminf(fmaxf(tau / T2, 0.f), 1.f) * (float)(N2-1);
      int i0 = (int)x; i0 = max(0, min(i0, N2-2));
      float w = x - (float)i0;
      float4 f0 = s2f4[(size_t)i0*32 + d32];
      float4 f1 = s2f4[(size_t)(i0+1)*32 + d32];
      float4 r;
      r.x = f0.x + (f1.x - f0.x)*w; r.y = f0.y + (f1.y - f0.y)*w;
      r.z = f0.z + (f1.z - f0.z)*w; r.w = f0.w + (f1.w - f0.w)*w;
      s2L4[k*33 + d32] = r;
    }
  }
  {
    const int mi = t >> 3, q = t & 7;
    const int m = mb*32 + mi;
    float twm = tw[b*MW + m];
    float x = fminf(fmaxf(twm / T1, 0.f), 1.f) * (float)(N1-1);
    int i0 = (int)x; i0 = max(0, min(i0, N1-2));
    float w = x - (float)i0;
    #pragma unroll
    for (int j = 0; j < 4; j++) {
      int d4 = q + 8*j;
      float4 f0 = s1f4[(size_t)i0*32 + d4];
      float4 f1 = s1f4[(size_t)(i0+1)*32 + d4];
      float4 r;
      r.x = f0.x + (f1.x - f0.x)*w; r.y = f0.y + (f1.y - f0.y)*w;
      r.z = f0.z + (f1.z - f0.z)*w; r.w = f0.w + (f1.w - f0.w)*w;
      s1L4[mi*33 + d4] = r;
    }
  }
  if (t < 32) {
    int m = mb*32 + t, g = b*MW + m;
    float twm = tw[g];
    float prev = (m > 0) ? tw[g-1] : twm;
    float next = (m < MW-1) ? tw[g+1] : twm;
    wtsL[t] = 0.5f*(next - prev);
    float lbm = glb_lb[g]*T2, ubm = glb_ub[g]*T2;
    lbL[t] = lbm; ubL[t] = ubm;
    matchL[t] = (feq(lbm, lb0) && feq(ubm, ub0)) ? 1 : 0;
  }
  __syncthreads();

  const int mi = t >> 3, kg = t & 7;
  const int m = mb*32 + mi;
  float acc[12];
  #pragma unroll
  for (int i = 0; i < 12; i++) acc[i] = 0.f;
  if (matchL[mi]) {
    for (int d4 = 0; d4 < 32; d4++) {
      float4 s1v = s1L4[mi*33 + d4];
      #pragma unroll
      for (int k12 = 0; k12 < 12; k12++) {
        int k = kg + 8*k12;
        float4 s2v = s2L4[k*33 + d4];
        float dx = s1v.x - s2v.x, dy = s1v.y - s2v.y;
        float dz = s1v.z - s2v.z, dw = s1v.w - s2v.w;
        acc[k12] += dx*dx + dy*dy + dz*dz + dw*dw;
      }
    }
  } else {
    const float lbm = lbL[mi], ubm = ubL[mi];
    int i0a[12]; float wa[12];
    #pragma unroll
    for (int k12 = 0; k12 < 12; k12++) {
      int k = kg + 8*k12;
      float tau = lbm + (ubm - lbm) * (float)k * (1.0f/95.0f);
      float x = fminf(fmaxf(tau / T2, 0.f), 1.f) * (float)(N2-1);
      int i0 = (int)x; i0 = max(0, min(i0, N2-2));
      i0a[k12] = i0; wa[k12] = x - (float)i0;
    }
    for (int d4 = 0; d4 < 32; d4++) {
      float4 s1v = s1L4[mi*33 + d4];
      #pragma unroll
      for (int k12 = 0; k12 < 12; k12++) {
        float4 f0 = s2f4[(size_t)i0a[k12]*32 + d4];
        float4 f1 = s2f4[(size_t)(i0a[k12]+1)*32 + d4];
        float w = wa[k12];
        float ax = f0.x + (f1.x - f0.x)*w, ay = f0.y + (f1.y - f0.y)*w;
        float az = f0.z + (f1.z - f0.z)*w, aw = f0.w + (f1.w - f0.w)*w;
        float dx = s1v.x - ax, dy = s1v.y - ay, dz = s1v.z - az, dw = s1v.w - aw;
        acc[k12] += dx*dx + dy*dy + dz*dz + dw*dw;
      }
    }
  }
  {
    const float wts = wtsL[mi];
    const float lbm = lbL[mi], ubm = ubL[mi];
    #pragma unroll
    for (int k12 = 0; k12 < 12; k12++) {
      int k = kg + 8*k12;
      float nodev = acc[k12] * wts;
      float tau = lbm + (ubm - lbm) * (float)k * (1.0f/95.0f);
      if (m == 0)    nodev += BARRIER * tau * tau;
      if (m == MW-1) { float dd = tau - T2; nodev += BARRIER * dd * dd; }
      ndt[mi*99 + k] = nodev;
    }
  }
  __syncthreads();
  float* nodeP = ws + WS_NODE + ((size_t)b*MW + mb*32)*KD;
  for (int idx = t; idx < 32*KD; idx += 256) {
    int mi2 = idx / KD, kv = idx - mi2*KD;
    nodeP[idx] = ndt[mi2*99 + kv];
  }
  if (t < 32) {
    float mn = 3e38f;
    for (int k = 0; k < KD; k++) mn = fminf(mn, ndt[t*99 + k]);
    ws[WS_NDMIN + b*MW + mb*32 + t] = mn;
  }
}

// ---------------- K2: prefix-sum DP (diagonal-exact fast path) ----------------
// When the in-band off-diagonal edge costs provably underflow (checked
// rigorously from the prefix sums themselves), the softmin DP reduces EXACTLY
// (in f32 and f64) to alpha_m[k] = sum_{i<=m} node_i[k] + m*rdt, and
// alpha+beta = S_total[k] + const -> logits are m-independent. Generic inputs
// fall back to the validated sequential register DP (round-5 code).
__global__ __launch_bounds__(128) void k2_dp(const float* __restrict__ tw,
                                             const float* __restrict__ glb_lb,
                                             const float* __restrict__ glb_ub,
                                             const float* __restrict__ reg_wt,
                                             const float* __restrict__ gubp,
                                             float* __restrict__ ws) {
  const int b = blockIdx.x;
  const int t = threadIdx.x;
  const int wv = t >> 6;
  const int lane = t & 63;
  __shared__ float ndL[MW*KD];   // 96 KB
  __shared__ float ndmL[MW];
  __shared__ float lbw[MW], ubw[MW], twv[MW];
  __shared__ float mir[2][KD];
  __shared__ float sred[8];
  __shared__ int skey[2];
  const float T2 = ws[WS_T2MAX + b];
  {
    const float4* np4 = (const float4*)(ws + WS_NODE + (size_t)b*MW*KD);
    float4* nl4 = (float4*)ndL;
    #pragma unroll
    for (int it = 0; it < (MW*KD/4)/128; it++)
      nl4[t + 128*it] = np4[t + 128*it];
    for (int i2 = t; i2 < MW; i2 += 128) {
      ndmL[i2] = ws[WS_NDMIN + b*MW + i2];
      lbw[i2] = glb_lb[b*MW+i2]*T2;
      ubw[i2] = glb_ub[b*MW+i2]*T2;
      twv[i2] = tw[b*MW+i2];
    }
  }
  const float r = reg_wt[b];
  const float gub = gubp[b];
  __syncthreads();

  // ---- checks: grid uniform across m, edge-cost floors, dt sanity ----
  const float lb0 = lbw[0], ub0 = ubw[0];
  const float g = (ub0 - lb0) * (1.0f/95.0f);
  bool keyok = true;
  float minE1 = 3e38f, minE2 = 3e38f, maxRdt = 0.f;
  for (int i = t; i < MW; i += 128)
    keyok = keyok && (lbw[i] == lb0) && (ubw[i] == ub0);
  for (int i = t; i < MW-1; i += 128) {
    float dtv = twv[i+1] - twv[i];
    if (!(dtv > 0.f)) keyok = false;
    else {
      float rdtv = r * dtv, sl = g / dtv;
      minE1 = fminf(minE1, fminf(edgec(sl, rdtv, gub), edgec(-sl, rdtv, gub)));
      minE2 = fminf(minE2, fminf(edgec(2.f*sl, rdtv, gub), edgec(-2.f*sl, rdtv, gub)));
      maxRdt = fmaxf(maxRdt, rdtv);
    }
  }

  // ---- prefix-sum scan with self-consistent adjacent-diff stat ----
  const bool actS = t < KD;
  const int k = actS ? t : (KD-1);
  float P = 0.f, P2 = 0.f, mx = 0.f;
  {
    const bool hasn = actS && (k < KD-1);
    #pragma unroll 4
    for (int m = 0; m < MW; m++) {
      float a = ndL[m*KD + k];
      float bq = hasn ? ndL[m*KD + k + 1] : a;
      P += a; P2 += bq;
      mx = fmaxf(mx, fabsf(P - P2));
    }
  }
  if (!actS) mx = 0.f;
  // block reduction of stats
  {
    float wmx = mx, wE1 = minE1, wE2 = minE2, wR = maxRdt;
    #pragma unroll
    for (int o = 32; o; o >>= 1) {
      wmx = fmaxf(wmx, __shfl_xor(wmx, o));
      wE1 = fminf(wE1, __shfl_xor(wE1, o));
      wE2 = fminf(wE2, __shfl_xor(wE2, o));
      wR  = fmaxf(wR,  __shfl_xor(wR,  o));
    }
    int ka = __all(keyok ? 1 : 0);
    if (lane == 0) {
      sred[wv*4+0] = wmx; sred[wv*4+1] = wE1;
      sred[wv*4+2] = wE2; sred[wv*4+3] = wR;
      skey[wv] = ka;
    }
  }
  __syncthreads();
  const float MX = fmaxf(sred[0], sred[4]);
  const float E1 = fminf(sred[1], sred[5]);
  const float E2 = fminf(sred[2], sred[6]);
  const float RD = fmaxf(sred[3], sred[7]);
  const bool ok = skey[0] && skey[1] &&
                  (2.0f*MX   <= E1 - RD - 3.0f) &&
                  (190.0f*MX <= E2 - RD - 3.0f);
  if (actS) ws[WS_LOGIT + b*KD + t] = P;
  if (t == 0) ws[WS_FLAG + b] = ok ? 0.f : 1.f;
  if (ok) return;

  // ---------- generic fallback: round-5 sequential register DP ----------
  {
    const int dir = t >> 6;
    const bool act = lane < 48;
    const int k0i = 2*lane, k1i = 2*lane+1;
    const float frk0 = (float)k0i*(1.f/95.f), frk1 = (float)k1i*(1.f/95.f);
    float* __restrict__ outP = ws + (dir ? WS_BBUF : WS_ABUF) + (size_t)b*MW*KD;

    float a0 = 3e38f, a1 = 3e38f;
    {
      const int m0 = dir ? (MW-1) : 0;
      if (act) {
        a0 = ndL[m0*KD + k0i]; a1 = ndL[m0*KD + k1i];
        mir[dir][k0i] = a0; mir[dir][k1i] = a1;
        float2 o; o.x = dir ? 0.f : a0; o.y = dir ? 0.f : a1;
        *(float2*)&outP[(size_t)m0*KD + k0i] = o;
      }
    }
    float Blo;
    {
      float bl = act ? fminf(a0, a1) : 3e38f;
      #pragma unroll
      for (int o = 1; o < 64; o <<= 1) bl = fminf(bl, __shfl_xor(bl, o));
      Blo = bl;
    }
    float e00=3e38f,e0m=3e38f,e0p=3e38f,e10=3e38f,e1m=3e38f,e1p=3e38f;
    float eo0=3e38f, eo1=3e38f, eminmin=0.f;
    float cL1=__int_as_float(0x7fc00000), cU1=cL1, cL2=cL1, cU2=cL1, cdt=cL1;

    float pL1, pU1, pL2, pU2, pt1, pt2, pnd0=0.f, pnd1=0.f, pndm;
    {
      const int i0_ = dir ? (MW-2) : 0;
      pL1=lbw[i0_]; pU1=ubw[i0_]; pL2=lbw[i0_+1]; pU2=ubw[i0_+1];
      pt1=twv[i0_]; pt2=twv[i0_+1];
      const int mn_ = dir ? i0_ : (i0_+1);
      if (act) { float2 v = *(const float2*)&ndL[mn_*KD + k0i]; pnd0=v.x; pnd1=v.y; }
      pndm = ndmL[mn_];
    }

    for (int step = 0; step < MW-1; step++) {
      const float L1=pL1, U1=pU1, L2=pL2, U2=pU2;
      const float dt = pt2 - pt1;
      const float nd0=pnd0, nd1=pnd1, ndmn=pndm;
      {
        const int sn = (step+1 < MW-1) ? (step+1) : step;
        const int in_ = dir ? (MW-2-sn) : sn;
        pL1=lbw[in_]; pU1=ubw[in_]; pL2=lbw[in_+1]; pU2=ubw[in_+1];
        pt1=twv[in_]; pt2=twv[in_+1];
        const int mn_ = dir ? in_ : (in_+1);
        if (act) { float2 v = *(const float2*)&ndL[mn_*KD + k0i]; pnd0=v.x; pnd1=v.y; }
        pndm = ndmL[mn_];
      }
      const bool kc = !(feq(L1,cL1)&&feq(U1,cU1)&&feq(L2,cL2)&&feq(U2,cU2)&&feq(dt,cdt));
      if (kc) {
        cL1=L1; cU1=U1; cL2=L2; cU2=U2; cdt=dt;
        float bl = act ? fminf(mir[dir][k0i], mir[dir][k1i]) : 3e38f;
        #pragma unroll
        for (int o = 1; o < 64; o <<= 1) bl = fminf(bl, __shfl_xor(bl, o));
        Blo = bl;
        const float invdt = 1.f/dt, rdt = r*dt;
        const float my0 = dir ? (L1+(U1-L1)*frk0) : (L2+(U2-L2)*frk0);
        const float my1 = dir ? (L1+(U1-L1)*frk1) : (L2+(U2-L2)*frk1);
        e00=3e38f; e0m=3e38f; e0p=3e38f; e10=3e38f; e1m=3e38f; e1p=3e38f;
        eo0=3e38f; eo1=3e38f;
        float emn = 3e38f;
        for (int j = 0; j < KD; j++) {
          const float frj = (float)j*(1.f/95.f);
          const float oth = dir ? (L2+(U2-L2)*frj) : (L1+(U1-L1)*frj);
          const float sl0 = (dir ? (oth-my0) : (my0-oth))*invdt;
          const float sl1 = (dir ? (oth-my1) : (my1-oth))*invdt;
          float d0=sl0-1.f, g0=fminf(sl0,0.f), v0=fmaxf(sl0-gub,0.f);
          float ej0 = rdt*d0*d0 + BARRIER*(g0*g0+v0*v0);
          float d1=sl1-1.f, g1=fminf(sl1,0.f), v1=fmaxf(sl1-gub,0.f);
          float ej1 = rdt*d1*d1 + BARRIER*(g1*g1+v1*v1);
          emn = fminf(emn, fminf(ej0, ej1));
          if      (j == k0i-1) e0m = ej0;
          else if (j == k0i)   e00 = ej0;
          else if (j == k0i+1) e0p = ej0;
          else                 eo0 = fminf(eo0, ej0);
          if      (j == k1i-1) e1m = ej1;
          else if (j == k1i)   e10 = ej1;
          else if (j == k1i+1) e1p = ej1;
          else                 eo1 = fminf(eo1, ej1);
        }
        if (!act) emn = 3e38f;
        #pragma unroll
        for (int o = 1; o < 64; o <<= 1) emn = fminf(emn, __shfl_xor(emn, o));
        eminmin = emn;
      }
      const float a1p = __shfl_up(a1, 1);
      const float a0n = __shfl_down(a0, 1);
      const float x0m = fminf(a1p + e0m, 3e38f);
      const float x00 = fminf(a0  + e00, 3e38f);
      const float x0p = fminf(a1  + e0p, 3e38f);
      const float x1m = fminf(a0  + e1m, 3e38f);
      const float x10 = fminf(a1  + e10, 3e38f);
      const float x1p = fminf(a0n + e1p, 3e38f);
      float mn0 = fminf(fminf(x0m, x00), x0p);
      float mn1 = fminf(fminf(x1m, x10), x1p);
      float sum0 = __expf((mn0-x0m)*INVG) + __expf((mn0-x00)*INVG) + __expf((mn0-x0p)*INVG);
      float sum1 = __expf((mn1-x1m)*INVG) + __expf((mn1-x10)*INVG) + __expf((mn1-x1p)*INVG);
      const bool bad = act && ((Blo + eo0 - mn0 < 8.7f) || (Blo + eo1 - mn1 < 8.7f));
      if (__any((int)bad)) {
        const float invdt = 1.f/dt, rdt = r*dt;
        const float my0 = dir ? (L1+(U1-L1)*frk0) : (L2+(U2-L2)*frk0);
        const float my1 = dir ? (L1+(U1-L1)*frk1) : (L2+(U2-L2)*frk1);
        mn0 = 3e38f; mn1 = 3e38f;
        for (int j = 0; j < KD; j++) {
          const float sj = mir[dir][j];
          const float frj = (float)j*(1.f/95.f);
          const float oth = dir ? (L2+(U2-L2)*frj) : (L1+(U1-L1)*frj);
          const float sl0 = (dir ? (oth-my0) : (my0-oth))*invdt;
          const float sl1 = (dir ? (oth-my1) : (my1-oth))*invdt;
          float d0=sl0-1.f, g0=fminf(sl0,0.f), v0=fmaxf(sl0-gub,0.f);
          float ej0 = rdt*d0*d0 + BARRIER*(g0*g0+v0*v0);
          float d1=sl1-1.f, g1=fminf(sl1,0.f), v1=fmaxf(sl1-gub,0.f);
          float ej1 = rdt*d1*d1 + BARRIER*(g1*g1+v1*v1);
          mn0 = fminf(mn0, fminf(sj + ej0, 3e38f));
          mn1 = fminf(mn1, fminf(sj + ej1, 3e38f));
        }
        sum0 = 0.f; sum1 = 0.f;
        for (int j = 0; j < KD; j++) {
          const float sj = mir[dir][j];
          const float frj = (float)j*(1.f/95.f);
          const float oth = dir ? (L2+(U2-L2)*frj) : (L1+(U1-L1)*frj);
          const float sl0 = (dir ? (oth-my0) : (my0-oth))*invdt;
          const float sl1 = (dir ? (oth-my1) : (my1-oth))*invdt;
          float d0=sl0-1.f, g0=fminf(sl0,0.f), v0=fmaxf(sl0-gub,0.f);
          float ej0 = rdt*d0*d0 + BARRIER*(g0*g0+v0*v0);
          float d1=sl1-1.f, g1=fminf(sl1,0.f), v1=fmaxf(sl1-gub,0.f);
          float ej1 = rdt*d1*d1 + BARRIER*(g1*g1+v1*v1);
          sum0 += __expf((mn0 - fminf(sj + ej0, 3e38f))*INVG);
          sum1 += __expf((mn1 - fminf(sj + ej1, 3e38f))*INVG);
        }
      }
      const float sv0 = mn0 - GAM*__logf(sum0);
      const float sv1 = mn1 - GAM*__logf(sum1);
      const float na0 = nd0 + sv0, na1 = nd1 + sv1;
      const int ic = dir ? (MW-2-step) : step;
      const int mnode = dir ? ic : (ic+1);
      if (act) {
        mir[dir][k0i] = na0; mir[dir][k1i] = na1;
        float2 o; o.x = dir ? sv0 : na0; o.y = dir ? sv1 : na1;
        *(float2*)&outP[(size_t)mnode*KD + k0i] = o;
      }
      a0 = act ? na0 : 3e38f;
      a1 = act ? na1 : 3e38f;
      Blo += eminmin + ndmn - 0.4575f;
    }
  }
}

// ---------------- K3: softmax readout ----------------
__global__ __launch_bounds__(256) void k3_final(const float* __restrict__ glb_lb,
                                                const float* __restrict__ glb_ub,
                                                const float* __restrict__ ws,
                                                float* __restrict__ out) {
  const int wv = threadIdx.x >> 6;
  const int lane = threadIdx.x & 63;
  const int gw = blockIdx.x * 4 + wv;      // b*256+m
  const int b = gw >> 8, m = gw & 255;
  const float T2 = ws[WS_T2MAX + b];
  const float lb = glb_lb[b*MW+m] * T2;
  const float ub = glb_ub[b*MW+m] * T2;
  const float flg = ws[WS_FLAG + b];
  float s0, s1 = 1e30f;
  if (flg == 0.f) {
    const float* __restrict__ Lp = ws + WS_LOGIT + b*KD;
    s0 = Lp[lane];
    if (lane < KD - 64) s1 = Lp[lane+64];
  } else {
    const float* __restrict__ Ab = ws + WS_ABUF + (size_t)gw*KD;
    const float* __restrict__ Bb = ws + WS_BBUF + (size_t)gw*KD;
    s0 = Ab[lane] + Bb[lane];
    if (lane < KD - 64) s1 = Ab[lane+64] + Bb[lane+64];
  }
  float mn = fminf(s0, s1);
  #pragma unroll
  for (int o = 32; o; o >>= 1) mn = fminf(mn, __shfl_xor(mn, o));
  const float tau0 = lb + (ub-lb) * (float)lane * (1.0f/95.0f);
  const float tau1 = lb + (ub-lb) * (float)(lane+64) * (1.0f/95.0f);
  float w0 = __expf((mn - s0) * INVG);
  float w1 = __expf((mn - s1) * INVG);
  float num = w0*tau0 + w1*tau1;
  float den = w0 + w1;
  #pragma unroll
  for (int o = 32; o; o >>= 1) {
    num += __shfl_down(num, o);
    den += __shfl_down(den, o);
  }
  if (lane == 0) out[gw] = num / den;
}

extern "C" void kernel_launch(void* const* d_in, const int* in_sizes, int n_in,
                              void* d_out, int out_size, void* d_ws, size_t ws_size,
                              hipStream_t stream) {
  const float* s1f    = (const float*)d_in[0];
  const float* s2f    = (const float*)d_in[1];
  const float* regw   = (const float*)d_in[2];
  const float* glb_lb = (const float*)d_in[3];
  const float* glb_ub = (const float*)d_in[4];
  const float* gubp   = (const float*)d_in[5];
  const float* t1     = (const float*)d_in[6];
  const float* t2     = (const float*)d_in[7];
  const float* twp    = (const float*)d_in[8];
  float* ws  = (float*)d_ws;
  float* out = (float*)d_out;

  k0_rowmax<<<NB, 256, 0, stream>>>(t1, t2, ws);
  dim3 g1(8, NB);
  k1_node<<<g1, 256, 0, stream>>>(s1f, s2f, twp, glb_lb, glb_ub, ws);
  k2_dp<<<NB, 128, 0, stream>>>(twp, glb_lb, glb_ub, regw, gubp, ws);
  k3_final<<<MW*NB/4, 256, 0, stream>>>(glb_lb, glb_ub, ws, out);
}